// Round 4
// baseline (275.711 us; speedup 1.0000x reference)
//
#include <hip/hip_runtime.h>
#include <stdint.h>

typedef short v8s __attribute__((ext_vector_type(8)));
typedef short v4s __attribute__((ext_vector_type(4)));
typedef float v4f __attribute__((ext_vector_type(4)));

#define AS1 __attribute__((address_space(1)))
#define AS3 __attribute__((address_space(3)))

__device__ __forceinline__ void glds16(const void* g, void* l) {
  __builtin_amdgcn_global_load_lds((const AS1 void*)g, (AS3 void*)l, 16, 0, 0);
}

__device__ __forceinline__ short f2bf(float f) {
  uint32_t u = __float_as_uint(f);
  u += 0x7fffu + ((u >> 16) & 1u);   // RNE; inputs are finite
  return (short)(u >> 16);
}

// ---------------- prep kernels ----------------

__global__ __launch_bounds__(256) void cast3_f32_bf16(
    const float* __restrict__ a, const float* __restrict__ b, const float* __restrict__ c,
    short* __restrict__ oa, short* __restrict__ ob, short* __restrict__ oc, int n4) {
  const float* in = (blockIdx.z == 0) ? a : (blockIdx.z == 1) ? b : c;
  short* out      = (blockIdx.z == 0) ? oa : (blockIdx.z == 1) ? ob : oc;
  int i = blockIdx.x * 256 + threadIdx.x;
  if (i < n4) {
    float4 v = ((const float4*)in)[i];
    short4 o = { f2bf(v.x), f2bf(v.y), f2bf(v.z), f2bf(v.w) };
    ((short4*)out)[i] = o;
  }
}

// in: Z slices of RxC fp32 row-major; out: Z slices of CxR bf16 row-major
__global__ __launch_bounds__(256) void transpose_cast(const float* __restrict__ in,
                                                      short* __restrict__ out, int R, int C) {
  __shared__ float tile[64][65];
  size_t sl = (size_t)blockIdx.z * R * C;
  in += sl; out += sl;
  int rb = blockIdx.x * 64, cb = blockIdx.y * 64;
  int t = threadIdx.x;
  int col = t & 63, r0 = t >> 6;
#pragma unroll
  for (int i = 0; i < 16; ++i) {
    int row = r0 + i * 4;
    tile[row][col] = in[(size_t)(rb + row) * C + cb + col];
  }
  __syncthreads();
#pragma unroll
  for (int i = 0; i < 16; ++i) {
    int orow = r0 + i * 4;
    out[(size_t)(cb + orow) * R + rb + col] = f2bf(tile[col][orow]);
  }
}

// fused per-head W transposes for Wq/Wk/Wv: z/16 picks tensor, z%16 the head slice
__global__ __launch_bounds__(256) void transpose_cast_w3(
    const float* __restrict__ wq, const float* __restrict__ wk, const float* __restrict__ wv,
    short* __restrict__ oq, short* __restrict__ ok, short* __restrict__ ov) {
  __shared__ float tile[64][65];
  const int which = blockIdx.z >> 4, slice = blockIdx.z & 15;
  const float* in = (which == 0) ? wq : (which == 1) ? wk : wv;
  short* out      = (which == 0) ? oq : (which == 1) ? ok : ov;
  const int R = 1024, C = 64;
  in  += (size_t)slice * R * C;
  out += (size_t)slice * R * C;
  int rb = blockIdx.x * 64;
  int t = threadIdx.x;
  int col = t & 63, r0 = t >> 6;
#pragma unroll
  for (int i = 0; i < 16; ++i) {
    int row = r0 + i * 4;
    tile[row][col] = in[(size_t)(rb + row) * C + col];
  }
  __syncthreads();
#pragma unroll
  for (int i = 0; i < 16; ++i) {
    int orow = r0 + i * 4;
    out[(size_t)orow * R + rb + col] = f2bf(tile[col][orow]);
  }
}

// ---------------- 128x128 GEMM core (m97 structure) ----------------
__device__ __forceinline__ void gemm_core128(const short* __restrict__ Ag,
                                             const short* __restrict__ Bg,
                                             short* As, short* Bs,
                                             v4f (&acc)[4][4]) {
  const int tid  = threadIdx.x;
  const int lane = tid & 63;
  const int w    = tid >> 6;
  const int quad = lane >> 4;
  const int c15  = lane & 15;
  const int wr   = (w >> 1) * 64;
  const int wc   = (w & 1) * 64;

  const int r0 = tid >> 2, p0 = tid & 3;
  const short* g0 = Ag + (size_t)r0 * 1024 + p0 * 8;
  const short* g1 = g0 + 64 * 1024;
  const short* h0 = Bg + (size_t)r0 * 1024 + p0 * 8;
  const short* h1 = h0 + 64 * 1024;
  short* lA0 = As + tid * 8;
  short* lA1 = As + (256 + tid) * 8;
  short* lB0 = Bs + tid * 8;
  short* lB1 = Bs + (256 + tid) * 8;

  for (int kb = 0; kb < 32; ++kb) {
    __syncthreads();
    glds16(g0, lA0); glds16(g1, lA1);
    glds16(h0, lB0); glds16(h1, lB1);
    g0 += 32; g1 += 32; h0 += 32; h1 += 32;
    __syncthreads();

    v8s a[4], b[4];
#pragma unroll
    for (int mt = 0; mt < 4; ++mt)
      a[mt] = *(const v8s*)(As + (wr + mt * 16 + c15) * 32 + quad * 8);
#pragma unroll
    for (int nt = 0; nt < 4; ++nt)
      b[nt] = *(const v8s*)(Bs + (wc + nt * 16 + c15) * 32 + quad * 8);
#pragma unroll
    for (int mt = 0; mt < 4; ++mt)
#pragma unroll
      for (int nt = 0; nt < 4; ++nt)
        acc[mt][nt] = __builtin_amdgcn_mfma_f32_16x16x32_bf16(a[mt], b[nt], acc[mt][nt], 0, 0, 0);
  }
}

// ---------------- QKV projection ----------------
__global__ __launch_bounds__(256, 2) void proj_gemm(
    const short* __restrict__ xQ, const short* __restrict__ xK, const short* __restrict__ xV,
    const short* __restrict__ WqT, const short* __restrict__ WkT, const short* __restrict__ WvT,
    const float* __restrict__ bq, const float* __restrict__ bk, const float* __restrict__ bv,
    short* __restrict__ Qb, short* __restrict__ Kb, short* __restrict__ Vtb) {
  __shared__ short As[4096];
  __shared__ short Bs[4096];
  const int z = blockIdx.z;
  const short* A    = (z == 0) ? xQ  : (z == 1) ? xK  : xV;
  const short* Bt   = (z == 0) ? WqT : (z == 1) ? WkT : WvT;
  const float* bias = (z == 0) ? bq  : (z == 1) ? bk  : bv;
  short* outp       = (z == 0) ? Qb  : (z == 1) ? Kb  : Vtb;
  const int mb = blockIdx.y * 128, nb = blockIdx.x * 128;
  v4f acc[4][4] = {};
  gemm_core128(A + (size_t)mb * 1024, Bt + (size_t)nb * 1024, As, Bs, acc);

  const int lane = threadIdx.x & 63, w = threadIdx.x >> 6;
  const int quad = lane >> 4, c15 = lane & 15;
  const int wr = (w >> 1) * 64, wc = (w & 1) * 64;
  const bool vmode = (z == 2);
#pragma unroll
  for (int nt = 0; nt < 4; ++nt) {
    const int gn = nb + wc + nt * 16 + c15;
    const float bb = bias[gn];
    const int h = gn >> 6, e = gn & 63;
#pragma unroll
    for (int mt = 0; mt < 4; ++mt) {
      if (!vmode) {
#pragma unroll
        for (int r = 0; r < 4; ++r) {
          const int gm = mb + wr + mt * 16 + quad * 4 + r;
          const int bi = gm >> 10, s = gm & 1023;
          const size_t base = (size_t)(bi * 16 + h) * 65536;
          outp[base + (size_t)s * 64 + e] = f2bf(acc[mt][nt][r] + bb);
        }
      } else {
        // r -> consecutive s: pack into one 8B store (32B contiguous per c15 group)
        const int gm0 = mb + wr + mt * 16 + quad * 4;
        const int bi = gm0 >> 10, s0 = gm0 & 1023;
        const size_t base = (size_t)(bi * 16 + h) * 65536;
        short4 st = { f2bf(acc[mt][nt][0] + bb), f2bf(acc[mt][nt][1] + bb),
                      f2bf(acc[mt][nt][2] + bb), f2bf(acc[mt][nt][3] + bb) };
        *(short4*)&outp[base + (size_t)e * 1024 + s0] = st;
      }
    }
  }
}

// ---------------- output projection ----------------
__global__ __launch_bounds__(256, 2) void out_gemm(
    const short* __restrict__ AV, const short* __restrict__ WoT,
    const float* __restrict__ bo, float* __restrict__ outp) {
  __shared__ short As[4096];
  __shared__ short Bs[4096];
  const int mb = blockIdx.y * 128, nb = blockIdx.x * 128;
  v4f acc[4][4] = {};
  gemm_core128(AV + (size_t)mb * 1024, WoT + (size_t)nb * 1024, As, Bs, acc);
  const int lane = threadIdx.x & 63, w = threadIdx.x >> 6;
  const int quad = lane >> 4, c15 = lane & 15;
  const int wr = (w >> 1) * 64, wc = (w & 1) * 64;
#pragma unroll
  for (int nt = 0; nt < 4; ++nt) {
    const int gn = nb + wc + nt * 16 + c15;
    const float bb = bo[gn];
#pragma unroll
    for (int mt = 0; mt < 4; ++mt)
#pragma unroll
      for (int r = 0; r < 4; ++r) {
        const int gm = mb + wr + mt * 16 + quad * 4 + r;
        outp[(size_t)gm * 1024 + gn] = acc[mt][nt][r] + bb;
      }
  }
}

// ---------------- flash attention (all-register, S^T trick, K prefetch) ----------------
// S^T = K*Q^T : C-layout row=key=quad*4+r, col=query=c15  ==  B-operand layout of
// mfma_f32_16x16x16_bf16 (k=quad*4+j, n=c15)  =>  P never leaves registers.
// O^T = V^T * P^T accumulated per (query-group mg, dh-tile t). No LDS, no barriers.
__global__ __launch_bounds__(256, 2) void attn_kernel(
    const short* __restrict__ Qb, const short* __restrict__ Kb,
    const short* __restrict__ Vtb, const int* __restrict__ lens,
    short* __restrict__ AVb) {
  const int tid = threadIdx.x, lane = tid & 63, w = tid >> 6;
  const int quad = lane >> 4, c15 = lane & 15;
  const int flat = blockIdx.x;
  const int bh = (flat & 7) + 8 * ((flat >> 3) & 7);   // XCD-L2 locality swizzle
  const int qg = flat >> 6;
  const int b = bh >> 4, h = bh & 15;
  const short* Qp = Qb  + (size_t)bh * 65536;
  const short* Kp = Kb  + (size_t)bh * 65536;
  const short* Vp = Vtb + (size_t)bh * 65536;
  const int len = lens[b];
  const int row0 = qg * 128 + w * 32;

  // Q as B-operand frags: B[n=query=c15][k=dh=kf*32+quad*8+j]
  v8s bq_[2][2];
#pragma unroll
  for (int mg = 0; mg < 2; ++mg)
#pragma unroll
    for (int kf = 0; kf < 2; ++kf)
      bq_[mg][kf] = *(const v8s*)(Qp + (size_t)(row0 + mg * 16 + c15) * 64 + kf * 32 + quad * 8);

  // per-query scale (query = c15 lane): 0.125 live, 0 masked (-> uniform softmax = ref)
  float scale[2];
#pragma unroll
  for (int mg = 0; mg < 2; ++mg)
    scale[mg] = (row0 + mg * 16 + c15 < len) ? 0.125f : 0.0f;

  float sm[2] = { 0.f, 0.f };
  v4f o[2][4] = {};          // O^T: row=dh=t*16+quad*4+r, col=query=c15

  // K as A-operand frags, double-buffered: A[m=key=c15][k=dh]
  v8s ak[2][4][2];
#pragma unroll
  for (int nt = 0; nt < 4; ++nt)
#pragma unroll
    for (int kf = 0; kf < 2; ++kf)
      ak[0][nt][kf] = *(const v8s*)(Kp + (size_t)(nt * 16 + c15) * 64 + kf * 32 + quad * 8);

#pragma unroll 4
  for (int kb = 0; kb < 16; ++kb) {
    const int cur = kb & 1, nxt = cur ^ 1;

    // prefetch next K block while this one computes
    if (kb < 15) {
      const short* kn = Kp + (size_t)(kb + 1) * 4096;
#pragma unroll
      for (int nt = 0; nt < 4; ++nt)
#pragma unroll
        for (int kf = 0; kf < 2; ++kf)
          ak[nxt][nt][kf] = *(const v8s*)(kn + (size_t)(nt * 16 + c15) * 64 + kf * 32 + quad * 8);
    }

    // V^T A-frags for 16x16x16: A[m=dh=c15 (tile t)][k=key=quad*4+j] — 8B contiguous
    v4s av[4][4];
    const short* vb = Vp + kb * 64;
#pragma unroll
    for (int t = 0; t < 4; ++t)
#pragma unroll
      for (int nt = 0; nt < 4; ++nt)
        av[t][nt] = *(const v4s*)(vb + (size_t)(t * 16 + c15) * 1024 + nt * 16 + quad * 4);

    // S^T = K Q^T
    v4f sc[2][4];
#pragma unroll
    for (int mg = 0; mg < 2; ++mg)
#pragma unroll
      for (int nt = 0; nt < 4; ++nt) {
        v4f z = {};
#pragma unroll
        for (int kf = 0; kf < 2; ++kf)
          z = __builtin_amdgcn_mfma_f32_16x16x32_bf16(ak[cur][nt][kf], bq_[mg][kf], z, 0, 0, 0);
        sc[mg][nt] = z;
      }

    // softmax numerator in-register; per-lane partial denominators
    v4s pb[2][4];
#pragma unroll
    for (int mg = 0; mg < 2; ++mg)
#pragma unroll
      for (int nt = 0; nt < 4; ++nt) {
        v4s pv;
#pragma unroll
        for (int r = 0; r < 4; ++r) {
          float p = __expf(sc[mg][nt][r] * scale[mg]);
          sm[mg] += p;
          pv[r] = f2bf(p);
        }
        pb[mg][nt] = pv;
      }

    // O^T += V^T P^T  (P^T straight from C-registers as B-operand)
#pragma unroll
    for (int mg = 0; mg < 2; ++mg)
#pragma unroll
      for (int t = 0; t < 4; ++t)
#pragma unroll
        for (int nt = 0; nt < 4; ++nt)
          o[mg][t] = __builtin_amdgcn_mfma_f32_16x16x16bf16_1k(av[t][nt], pb[mg][nt], o[mg][t], 0, 0, 0);
  }

  // denominator: keys are spread over quads only (r and nt summed in-lane)
#pragma unroll
  for (int mg = 0; mg < 2; ++mg) {
    sm[mg] += __shfl_xor(sm[mg], 16);
    sm[mg] += __shfl_xor(sm[mg], 32);
  }

#pragma unroll
  for (int mg = 0; mg < 2; ++mg) {
    const float inv = 1.0f / sm[mg];
    const size_t rowbase = (size_t)(b * 1024 + row0 + mg * 16 + c15) * 1024 + h * 64;
#pragma unroll
    for (int t = 0; t < 4; ++t) {
      short4 st = { f2bf(o[mg][t][0] * inv), f2bf(o[mg][t][1] * inv),
                    f2bf(o[mg][t][2] * inv), f2bf(o[mg][t][3] * inv) };
      *(short4*)&AVb[rowbase + t * 16 + quad * 4] = st;
    }
  }
}

// ---------------- launch ----------------
extern "C" void kernel_launch(void* const* d_in, const int* in_sizes, int n_in,
                              void* d_out, int out_size, void* d_ws, size_t ws_size,
                              hipStream_t stream) {
  const float* xQ = (const float*)d_in[0];
  const float* xK = (const float*)d_in[1];
  const float* xV = (const float*)d_in[2];
  const int* lens = (const int*)d_in[3];
  const float* Wq = (const float*)d_in[4];
  const float* bq = (const float*)d_in[5];
  const float* Wk = (const float*)d_in[6];
  const float* bk = (const float*)d_in[7];
  const float* Wv = (const float*)d_in[8];
  const float* bv = (const float*)d_in[9];
  const float* Wo = (const float*)d_in[10];
  const float* bo = (const float*)d_in[11];
  float* out = (float*)d_out;

  char* ws = (char*)d_ws;
  short* xQb = (short*)(ws + 0);                 // 8 MB  [4096][1024] bf16
  short* xKb = (short*)(ws + 8388608);
  short* xVb = (short*)(ws + 16777216);
  short* WqT = (short*)(ws + 25165824);          // 2 MB  [n=h*64+e][d]
  short* WkT = (short*)(ws + 27262976);
  short* WvT = (short*)(ws + 29360128);
  short* WoT = (short*)(ws + 31457280);          // 2 MB  Wo^T [n][k]
  short* Qb  = (short*)(ws + 33554432);          // 8 MB  [b,h,s,e]
  short* Kb  = (short*)(ws + 41943040);          // 8 MB  [b,h,s,e]
  short* Vtb = (short*)(ws + 50331648);          // 8 MB  [b,h,e,s]
  short* AVb = (short*)(ws + 58720256);          // 8 MB  [b,s,h*64+e]

  cast3_f32_bf16<<<dim3(4096, 1, 3), 256, 0, stream>>>(xQ, xK, xV, xQb, xKb, xVb, 1048576);
  transpose_cast_w3<<<dim3(16, 1, 48), 256, 0, stream>>>(Wq, Wk, Wv, WqT, WkT, WvT);
  transpose_cast<<<dim3(16, 16, 1), 256, 0, stream>>>(Wo, WoT, 1024, 1024);
  proj_gemm<<<dim3(8, 32, 3), 256, 0, stream>>>(xQb, xKb, xVb, WqT, WkT, WvT,
                                                bq, bk, bv, Qb, Kb, Vtb);
  attn_kernel<<<dim3(512), 256, 0, stream>>>(Qb, Kb, Vtb, lens, AVb);
  out_gemm<<<dim3(8, 32, 1), 256, 0, stream>>>(AVb, WoT, bo, out);
}

// Round 5
// 217.035 us; speedup vs baseline: 1.2704x; 1.2704x over previous
//
#include <hip/hip_runtime.h>
#include <stdint.h>

typedef short v8s __attribute__((ext_vector_type(8)));
typedef short v4s __attribute__((ext_vector_type(4)));
typedef float v4f __attribute__((ext_vector_type(4)));

#define AS1 __attribute__((address_space(1)))
#define AS3 __attribute__((address_space(3)))

__device__ __forceinline__ void glds16(const void* g, void* l) {
  __builtin_amdgcn_global_load_lds((const AS1 void*)g, (AS3 void*)l, 16, 0, 0);
}

__device__ __forceinline__ short f2bf(float f) {
  uint32_t u = __float_as_uint(f);
  u += 0x7fffu + ((u >> 16) & 1u);   // RNE; inputs are finite
  return (short)(u >> 16);
}

// ---------------- prep kernels ----------------

__global__ __launch_bounds__(256) void cast3_f32_bf16(
    const float* __restrict__ a, const float* __restrict__ b, const float* __restrict__ c,
    short* __restrict__ oa, short* __restrict__ ob, short* __restrict__ oc, int n4) {
  const float* in = (blockIdx.z == 0) ? a : (blockIdx.z == 1) ? b : c;
  short* out      = (blockIdx.z == 0) ? oa : (blockIdx.z == 1) ? ob : oc;
  int i = blockIdx.x * 256 + threadIdx.x;
  if (i < n4) {
    float4 v = ((const float4*)in)[i];
    short4 o = { f2bf(v.x), f2bf(v.y), f2bf(v.z), f2bf(v.w) };
    ((short4*)out)[i] = o;
  }
}

// in: Z slices of RxC fp32 row-major; out: Z slices of CxR bf16 row-major
__global__ __launch_bounds__(256) void transpose_cast(const float* __restrict__ in,
                                                      short* __restrict__ out, int R, int C) {
  __shared__ float tile[64][65];
  size_t sl = (size_t)blockIdx.z * R * C;
  in += sl; out += sl;
  int rb = blockIdx.x * 64, cb = blockIdx.y * 64;
  int t = threadIdx.x;
  int col = t & 63, r0 = t >> 6;
#pragma unroll
  for (int i = 0; i < 16; ++i) {
    int row = r0 + i * 4;
    tile[row][col] = in[(size_t)(rb + row) * C + cb + col];
  }
  __syncthreads();
#pragma unroll
  for (int i = 0; i < 16; ++i) {
    int orow = r0 + i * 4;
    out[(size_t)(cb + orow) * R + rb + col] = f2bf(tile[col][orow]);
  }
}

// fused per-head W transposes for Wq/Wk/Wv: z/16 picks tensor, z%16 the head slice
__global__ __launch_bounds__(256) void transpose_cast_w3(
    const float* __restrict__ wq, const float* __restrict__ wk, const float* __restrict__ wv,
    short* __restrict__ oq, short* __restrict__ ok, short* __restrict__ ov) {
  __shared__ float tile[64][65];
  const int which = blockIdx.z >> 4, slice = blockIdx.z & 15;
  const float* in = (which == 0) ? wq : (which == 1) ? wk : wv;
  short* out      = (which == 0) ? oq : (which == 1) ? ok : ov;
  const int R = 1024, C = 64;
  in  += (size_t)slice * R * C;
  out += (size_t)slice * R * C;
  int rb = blockIdx.x * 64;
  int t = threadIdx.x;
  int col = t & 63, r0 = t >> 6;
#pragma unroll
  for (int i = 0; i < 16; ++i) {
    int row = r0 + i * 4;
    tile[row][col] = in[(size_t)(rb + row) * C + col];
  }
  __syncthreads();
#pragma unroll
  for (int i = 0; i < 16; ++i) {
    int orow = r0 + i * 4;
    out[(size_t)orow * R + rb + col] = f2bf(tile[col][orow]);
  }
}

// ---------------- 128x128 GEMM core (m97 structure) ----------------
__device__ __forceinline__ void gemm_core128(const short* __restrict__ Ag,
                                             const short* __restrict__ Bg,
                                             short* As, short* Bs,
                                             v4f (&acc)[4][4]) {
  const int tid  = threadIdx.x;
  const int lane = tid & 63;
  const int w    = tid >> 6;
  const int quad = lane >> 4;
  const int c15  = lane & 15;
  const int wr   = (w >> 1) * 64;
  const int wc   = (w & 1) * 64;

  const int r0 = tid >> 2, p0 = tid & 3;
  const short* g0 = Ag + (size_t)r0 * 1024 + p0 * 8;
  const short* g1 = g0 + 64 * 1024;
  const short* h0 = Bg + (size_t)r0 * 1024 + p0 * 8;
  const short* h1 = h0 + 64 * 1024;
  short* lA0 = As + tid * 8;
  short* lA1 = As + (256 + tid) * 8;
  short* lB0 = Bs + tid * 8;
  short* lB1 = Bs + (256 + tid) * 8;

  for (int kb = 0; kb < 32; ++kb) {
    __syncthreads();
    glds16(g0, lA0); glds16(g1, lA1);
    glds16(h0, lB0); glds16(h1, lB1);
    g0 += 32; g1 += 32; h0 += 32; h1 += 32;
    __syncthreads();

    v8s a[4], b[4];
#pragma unroll
    for (int mt = 0; mt < 4; ++mt)
      a[mt] = *(const v8s*)(As + (wr + mt * 16 + c15) * 32 + quad * 8);
#pragma unroll
    for (int nt = 0; nt < 4; ++nt)
      b[nt] = *(const v8s*)(Bs + (wc + nt * 16 + c15) * 32 + quad * 8);
#pragma unroll
    for (int mt = 0; mt < 4; ++mt)
#pragma unroll
      for (int nt = 0; nt < 4; ++nt)
        acc[mt][nt] = __builtin_amdgcn_mfma_f32_16x16x32_bf16(a[mt], b[nt], acc[mt][nt], 0, 0, 0);
  }
}

// ---------------- QKV projection ----------------
__global__ __launch_bounds__(256, 2) void proj_gemm(
    const short* __restrict__ xQ, const short* __restrict__ xK, const short* __restrict__ xV,
    const short* __restrict__ WqT, const short* __restrict__ WkT, const short* __restrict__ WvT,
    const float* __restrict__ bq, const float* __restrict__ bk, const float* __restrict__ bv,
    short* __restrict__ Qb, short* __restrict__ Kb, short* __restrict__ Vtb) {
  __shared__ short As[4096];
  __shared__ short Bs[4096];
  const int z = blockIdx.z;
  const short* A    = (z == 0) ? xQ  : (z == 1) ? xK  : xV;
  const short* Bt   = (z == 0) ? WqT : (z == 1) ? WkT : WvT;
  const float* bias = (z == 0) ? bq  : (z == 1) ? bk  : bv;
  short* outp       = (z == 0) ? Qb  : (z == 1) ? Kb  : Vtb;
  const int mb = blockIdx.y * 128, nb = blockIdx.x * 128;
  v4f acc[4][4] = {};
  gemm_core128(A + (size_t)mb * 1024, Bt + (size_t)nb * 1024, As, Bs, acc);

  const int lane = threadIdx.x & 63, w = threadIdx.x >> 6;
  const int quad = lane >> 4, c15 = lane & 15;
  const int wr = (w >> 1) * 64, wc = (w & 1) * 64;
  const bool vmode = (z == 2);
#pragma unroll
  for (int nt = 0; nt < 4; ++nt) {
    const int gn = nb + wc + nt * 16 + c15;
    const float bb = bias[gn];
    const int h = gn >> 6, e = gn & 63;
#pragma unroll
    for (int mt = 0; mt < 4; ++mt) {
      if (!vmode) {
#pragma unroll
        for (int r = 0; r < 4; ++r) {
          const int gm = mb + wr + mt * 16 + quad * 4 + r;
          const int bi = gm >> 10, s = gm & 1023;
          const size_t base = (size_t)(bi * 16 + h) * 65536;
          outp[base + (size_t)s * 64 + e] = f2bf(acc[mt][nt][r] + bb);
        }
      } else {
        const int gm0 = mb + wr + mt * 16 + quad * 4;
        const int bi = gm0 >> 10, s0 = gm0 & 1023;
        const size_t base = (size_t)(bi * 16 + h) * 65536;
        short4 st = { f2bf(acc[mt][nt][0] + bb), f2bf(acc[mt][nt][1] + bb),
                      f2bf(acc[mt][nt][2] + bb), f2bf(acc[mt][nt][3] + bb) };
        *(short4*)&outp[base + (size_t)e * 1024 + s0] = st;
      }
    }
  }
}

// ---------------- output projection ----------------
__global__ __launch_bounds__(256, 2) void out_gemm(
    const short* __restrict__ AV, const short* __restrict__ WoT,
    const float* __restrict__ bo, float* __restrict__ outp) {
  __shared__ short As[4096];
  __shared__ short Bs[4096];
  const int mb = blockIdx.y * 128, nb = blockIdx.x * 128;
  v4f acc[4][4] = {};
  gemm_core128(AV + (size_t)mb * 1024, WoT + (size_t)nb * 1024, As, Bs, acc);
  const int lane = threadIdx.x & 63, w = threadIdx.x >> 6;
  const int quad = lane >> 4, c15 = lane & 15;
  const int wr = (w >> 1) * 64, wc = (w & 1) * 64;
#pragma unroll
  for (int nt = 0; nt < 4; ++nt) {
    const int gn = nb + wc + nt * 16 + c15;
    const float bb = bo[gn];
#pragma unroll
    for (int mt = 0; mt < 4; ++mt)
#pragma unroll
      for (int r = 0; r < 4; ++r) {
        const int gm = mb + wr + mt * 16 + quad * 4 + r;
        outp[(size_t)gm * 1024 + gn] = acc[mt][nt][r] + bb;
      }
  }
}

// ---------------- flash attention ----------------
// LDS-staged K/V (glds DMA, XOR-swizzled layout, single-barrier double buffer),
// S^T = K*Q^T in registers -> P^T feeds mfma_16x16x16bf16_1k directly (no P LDS).
// Block: 128 q-rows (4 waves x 32), grid 512, 2 blocks/CU.
// LDS tile layout: row r (64 rows, 128 B), 16B-part p holds global part p^(r&7).
__global__ __launch_bounds__(256, 2) void attn_kernel(
    const short* __restrict__ Qb, const short* __restrict__ Kb,
    const short* __restrict__ Vtb, const int* __restrict__ lens,
    short* __restrict__ AVb) {
  __shared__ short Ks[2][4096];
  __shared__ short Vs[2][4096];
  const int tid = threadIdx.x, lane = tid & 63, w = tid >> 6;
  const int quad = lane >> 4, c15 = lane & 15;
  const int flat = blockIdx.x;
  const int bh = (flat & 7) + 8 * ((flat >> 3) & 7);   // XCD-L2 locality swizzle
  const int qg = flat >> 6;
  const int b = bh >> 4, h = bh & 15;
  const short* Qp = Qb  + (size_t)bh * 65536;
  const short* Kp = Kb  + (size_t)bh * 65536;
  const short* Vp = Vtb + (size_t)bh * 65536;
  const int len = lens[b];
  const int row0 = qg * 128 + w * 32;

  // Q as B-operand frags: B[n=query=c15][k=dh=kf*32+quad*8+j]
  v8s bq_[2][2];
#pragma unroll
  for (int mg = 0; mg < 2; ++mg)
#pragma unroll
    for (int kf = 0; kf < 2; ++kf)
      bq_[mg][kf] = *(const v8s*)(Qp + (size_t)(row0 + mg * 16 + c15) * 64 + kf * 32 + quad * 8);

  float scale[2];
#pragma unroll
  for (int mg = 0; mg < 2; ++mg)
    scale[mg] = (row0 + mg * 16 + c15 < len) ? 0.125f : 0.0f;

  float sm[2] = { 0.f, 0.f };
  v4f o[2][4] = {};          // O^T: row=dh=t*16+quad*4+r, col=query=c15

  // staging geometry: chunk c -> row=c>>3, part=c&7; thread does chunks tid, tid+256.
  // swizzle: LDS[row][part] <- global[row][part ^ (row&7)]; (row+32)&7 == row&7.
  const int srow = tid >> 3, spart = tid & 7;
  const int gpart = spart ^ (srow & 7);
  const int kgo0 = srow * 64 + gpart * 8, kgo1 = (srow + 32) * 64 + gpart * 8;
  const int vgo0 = srow * 1024 + gpart * 8, vgo1 = (srow + 32) * 1024 + gpart * 8;
  const int l0 = tid * 8, l1 = 2048 + tid * 8;

  // read-side swizzled offsets (bytes)
  const int c7 = c15 & 7;
  const int krow = c15 * 128;
  const int koff0 = krow + ((quad) ^ c7) * 16;        // kf=0: part=quad
  const int koff1 = krow + ((4 + quad) ^ c7) * 16;    // kf=1: part=4+quad
  const int q2 = quad >> 1, h8 = (quad & 1) * 8;
  int voff[4];
#pragma unroll
  for (int nt = 0; nt < 4; ++nt)
    voff[nt] = krow + ((2 * nt + q2) ^ c7) * 16 + h8;

  // preload buffer 0
  glds16(Kp + kgo0, (char*)Ks[0] + l0 * 2);
  glds16(Kp + kgo1, (char*)Ks[0] + l1 * 2);
  glds16(Vp + vgo0, (char*)Vs[0] + l0 * 2);
  glds16(Vp + vgo1, (char*)Vs[0] + l1 * 2);

  for (int kb = 0; kb < 16; ++kb) {
    const int cur = kb & 1, nxt = cur ^ 1;
    __syncthreads();   // drains DMA into cur; guards nxt against last iter's readers

    if (kb < 15) {     // prefetch next block; lands before NEXT barrier
      const short* kt = Kp + (size_t)(kb + 1) * 4096;
      const short* vt = Vp + (kb + 1) * 64;
      glds16(kt + kgo0, (char*)Ks[nxt] + l0 * 2);
      glds16(kt + kgo1, (char*)Ks[nxt] + l1 * 2);
      glds16(vt + vgo0, (char*)Vs[nxt] + l0 * 2);
      glds16(vt + vgo1, (char*)Vs[nxt] + l1 * 2);
    }

    // K A-frags from LDS: A[m=key=c15][k=dh]
    v8s ak[4][2];
#pragma unroll
    for (int nt = 0; nt < 4; ++nt) {
      ak[nt][0] = *(const v8s*)((const char*)Ks[cur] + nt * 2048 + koff0);
      ak[nt][1] = *(const v8s*)((const char*)Ks[cur] + nt * 2048 + koff1);
    }
    // V^T A-frags (x16): A[m=dh=t*16+c15][k=key=nt*16+quad*4+j]
    v4s av[4][4];
#pragma unroll
    for (int t = 0; t < 4; ++t)
#pragma unroll
      for (int nt = 0; nt < 4; ++nt)
        av[t][nt] = *(const v4s*)((const char*)Vs[cur] + t * 2048 + voff[nt]);

    // S^T = K Q^T
    v4f sc[2][4];
#pragma unroll
    for (int mg = 0; mg < 2; ++mg)
#pragma unroll
      for (int nt = 0; nt < 4; ++nt) {
        v4f z = {};
#pragma unroll
        for (int kf = 0; kf < 2; ++kf)
          z = __builtin_amdgcn_mfma_f32_16x16x32_bf16(ak[nt][kf], bq_[mg][kf], z, 0, 0, 0);
        sc[mg][nt] = z;
      }

    // softmax numerator in-register (per-query scale/mask on col lane c15)
    v4s pb[2][4];
#pragma unroll
    for (int mg = 0; mg < 2; ++mg)
#pragma unroll
      for (int nt = 0; nt < 4; ++nt) {
        v4s pv;
#pragma unroll
        for (int r = 0; r < 4; ++r) {
          float p = __expf(sc[mg][nt][r] * scale[mg]);
          sm[mg] += p;
          pv[r] = f2bf(p);
        }
        pb[mg][nt] = pv;
      }

    // O^T += V^T P^T  (P^T straight from C-registers as B-operand of x16)
#pragma unroll
    for (int mg = 0; mg < 2; ++mg)
#pragma unroll
      for (int t = 0; t < 4; ++t)
#pragma unroll
        for (int nt = 0; nt < 4; ++nt)
          o[mg][t] = __builtin_amdgcn_mfma_f32_16x16x16bf16_1k(av[t][nt], pb[mg][nt], o[mg][t], 0, 0, 0);
  }

  // denominator: keys spread over quads only (r, nt summed in-lane)
#pragma unroll
  for (int mg = 0; mg < 2; ++mg) {
    sm[mg] += __shfl_xor(sm[mg], 16);
    sm[mg] += __shfl_xor(sm[mg], 32);
  }

#pragma unroll
  for (int mg = 0; mg < 2; ++mg) {
    const float inv = 1.0f / sm[mg];
    const size_t rowbase = (size_t)(b * 1024 + row0 + mg * 16 + c15) * 1024 + h * 64;
#pragma unroll
    for (int t = 0; t < 4; ++t) {
      short4 st = { f2bf(o[mg][t][0] * inv), f2bf(o[mg][t][1] * inv),
                    f2bf(o[mg][t][2] * inv), f2bf(o[mg][t][3] * inv) };
      *(short4*)&AVb[rowbase + t * 16 + quad * 4] = st;
    }
  }
}

// ---------------- launch ----------------
extern "C" void kernel_launch(void* const* d_in, const int* in_sizes, int n_in,
                              void* d_out, int out_size, void* d_ws, size_t ws_size,
                              hipStream_t stream) {
  const float* xQ = (const float*)d_in[0];
  const float* xK = (const float*)d_in[1];
  const float* xV = (const float*)d_in[2];
  const int* lens = (const int*)d_in[3];
  const float* Wq = (const float*)d_in[4];
  const float* bq = (const float*)d_in[5];
  const float* Wk = (const float*)d_in[6];
  const float* bk = (const float*)d_in[7];
  const float* Wv = (const float*)d_in[8];
  const float* bv = (const float*)d_in[9];
  const float* Wo = (const float*)d_in[10];
  const float* bo = (const float*)d_in[11];
  float* out = (float*)d_out;

  char* ws = (char*)d_ws;
  short* xQb = (short*)(ws + 0);                 // 8 MB  [4096][1024] bf16
  short* xKb = (short*)(ws + 8388608);
  short* xVb = (short*)(ws + 16777216);
  short* WqT = (short*)(ws + 25165824);          // 2 MB  [n=h*64+e][d]
  short* WkT = (short*)(ws + 27262976);
  short* WvT = (short*)(ws + 29360128);
  short* WoT = (short*)(ws + 31457280);          // 2 MB  Wo^T [n][k]
  short* Qb  = (short*)(ws + 33554432);          // 8 MB  [b,h,s,e]
  short* Kb  = (short*)(ws + 41943040);          // 8 MB  [b,h,s,e]
  short* Vtb = (short*)(ws + 50331648);          // 8 MB  [b,h,e,s]
  short* AVb = (short*)(ws + 58720256);          // 8 MB  [b,s,h*64+e]

  cast3_f32_bf16<<<dim3(4096, 1, 3), 256, 0, stream>>>(xQ, xK, xV, xQb, xKb, xVb, 1048576);
  transpose_cast_w3<<<dim3(16, 1, 48), 256, 0, stream>>>(Wq, Wk, Wv, WqT, WkT, WvT);
  transpose_cast<<<dim3(16, 16, 1), 256, 0, stream>>>(Wo, WoT, 1024, 1024);
  proj_gemm<<<dim3(8, 32, 3), 256, 0, stream>>>(xQb, xKb, xVb, WqT, WkT, WvT,
                                                bq, bk, bv, Qb, Kb, Vtb);
  attn_kernel<<<dim3(512), 256, 0, stream>>>(Qb, Kb, Vtb, lens, AVb);
  out_gemm<<<dim3(8, 32, 1), 256, 0, stream>>>(AVb, WoT, bo, out);
}

// Round 6
// 209.536 us; speedup vs baseline: 1.3158x; 1.0358x over previous
//
#include <hip/hip_runtime.h>
#include <stdint.h>

typedef short v8s __attribute__((ext_vector_type(8)));
typedef short v4s __attribute__((ext_vector_type(4)));
typedef float v4f __attribute__((ext_vector_type(4)));

#define AS1 __attribute__((address_space(1)))
#define AS3 __attribute__((address_space(3)))

__device__ __forceinline__ void glds16(const void* g, void* l) {
  __builtin_amdgcn_global_load_lds((const AS1 void*)g, (AS3 void*)l, 16, 0, 0);
}

__device__ __forceinline__ short f2bf(float f) {
  uint32_t u = __float_as_uint(f);
  u += 0x7fffu + ((u >> 16) & 1u);   // RNE; inputs are finite
  return (short)(u >> 16);
}

// ---------------- prep kernels ----------------

__global__ __launch_bounds__(256) void cast3_f32_bf16(
    const float* __restrict__ a, const float* __restrict__ b, const float* __restrict__ c,
    short* __restrict__ oa, short* __restrict__ ob, short* __restrict__ oc, int n4) {
  const float* in = (blockIdx.z == 0) ? a : (blockIdx.z == 1) ? b : c;
  short* out      = (blockIdx.z == 0) ? oa : (blockIdx.z == 1) ? ob : oc;
  int i = blockIdx.x * 256 + threadIdx.x;
  if (i < n4) {
    float4 v = ((const float4*)in)[i];
    short4 o = { f2bf(v.x), f2bf(v.y), f2bf(v.z), f2bf(v.w) };
    ((short4*)out)[i] = o;
  }
}

// All weight transposes in one dispatch. grid (16,16,4):
//  z<3 : per-head W (z picks Wq/Wk/Wv), slice=blockIdx.y, rb=blockIdx.x*64, 1024x64 -> 64x1024
//  z=3 : Wo 1024x1024 -> WoT, rb=blockIdx.x*64, cb=blockIdx.y*64
__global__ __launch_bounds__(256) void transpose_w_all(
    const float* __restrict__ wq, const float* __restrict__ wk, const float* __restrict__ wv,
    const float* __restrict__ wo,
    short* __restrict__ oq, short* __restrict__ ok, short* __restrict__ ov,
    short* __restrict__ oo) {
  __shared__ float tile[64][65];
  const int z = blockIdx.z;
  const float* in;
  short* out;
  int C, R, rb, cb;
  if (z < 3) {
    const int slice = blockIdx.y;
    in  = ((z == 0) ? wq : (z == 1) ? wk : wv) + (size_t)slice * 65536;
    out = ((z == 0) ? oq : (z == 1) ? ok : ov) + (size_t)slice * 65536;
    C = 64; R = 1024; rb = blockIdx.x * 64; cb = 0;
  } else {
    in = wo; out = oo;
    C = 1024; R = 1024; rb = blockIdx.x * 64; cb = blockIdx.y * 64;
  }
  int t = threadIdx.x;
  int col = t & 63, r0 = t >> 6;
#pragma unroll
  for (int i = 0; i < 16; ++i) {
    int row = r0 + i * 4;
    tile[row][col] = in[(size_t)(rb + row) * C + cb + col];
  }
  __syncthreads();
#pragma unroll
  for (int i = 0; i < 16; ++i) {
    int orow = r0 + i * 4;
    out[(size_t)(cb + orow) * R + rb + col] = f2bf(tile[col][orow]);
  }
}

// ---------------- MRx128 GEMM core (m97 structure), MR in {64,128} ----------------
// A: [M x 1024] bf16 row-major, Bt: [N x 1024] bf16 row-major (B^T), K=1024, BK=32.
// Waves 2x2; per-wave rows = MR/2 (MT=MR/32 m-frags), cols 64 (4 n-frags).
template <int MR>
__device__ __forceinline__ void gemm_core(const short* __restrict__ Ag,
                                          const short* __restrict__ Bg,
                                          short* As, short* Bs,
                                          v4f (&acc)[MR / 32][4]) {
  constexpr int MT = MR / 32;
  const int tid  = threadIdx.x;
  const int lane = tid & 63;
  const int w    = tid >> 6;
  const int quad = lane >> 4;
  const int c15  = lane & 15;
  const int wr   = (w >> 1) * (MR / 2);
  const int wc   = (w & 1) * 64;

  // staging: chunk c -> row=c>>2, 16B part=c&3 ; LDS slot = c*16B  (layout [row][32])
  const int r0 = tid >> 2, p0 = tid & 3;
  const short* g0 = Ag + (size_t)r0 * 1024 + p0 * 8;
  const short* g1 = g0 + 64 * 1024;               // used only when MR==128
  const short* h0 = Bg + (size_t)r0 * 1024 + p0 * 8;
  const short* h1 = h0 + 64 * 1024;
  short* lA0 = As + tid * 8;
  short* lA1 = As + (256 + tid) * 8;
  short* lB0 = Bs + tid * 8;
  short* lB1 = Bs + (256 + tid) * 8;

  for (int kb = 0; kb < 32; ++kb) {
    __syncthreads();
    glds16(g0, lA0);
    if constexpr (MR == 128) glds16(g1, lA1);
    glds16(h0, lB0); glds16(h1, lB1);
    g0 += 32; h0 += 32; h1 += 32;
    if constexpr (MR == 128) g1 += 32;
    __syncthreads();

    v8s a[MT], b[4];
#pragma unroll
    for (int mt = 0; mt < MT; ++mt)
      a[mt] = *(const v8s*)(As + (wr + mt * 16 + c15) * 32 + quad * 8);
#pragma unroll
    for (int nt = 0; nt < 4; ++nt)
      b[nt] = *(const v8s*)(Bs + (wc + nt * 16 + c15) * 32 + quad * 8);
#pragma unroll
    for (int mt = 0; mt < MT; ++mt)
#pragma unroll
      for (int nt = 0; nt < 4; ++nt)
        acc[mt][nt] = __builtin_amdgcn_mfma_f32_16x16x32_bf16(a[mt], b[nt], acc[mt][nt], 0, 0, 0);
  }
}

// ---------------- QKV projection (128x128 tiles) ----------------
__global__ __launch_bounds__(256, 3) void proj_gemm(
    const short* __restrict__ xQ, const short* __restrict__ xK, const short* __restrict__ xV,
    const short* __restrict__ WqT, const short* __restrict__ WkT, const short* __restrict__ WvT,
    const float* __restrict__ bq, const float* __restrict__ bk, const float* __restrict__ bv,
    short* __restrict__ Qb, short* __restrict__ Kb, short* __restrict__ Vtb) {
  __shared__ short As[4096];
  __shared__ short Bs[4096];
  const int z = blockIdx.z;
  const short* A    = (z == 0) ? xQ  : (z == 1) ? xK  : xV;
  const short* Bt   = (z == 0) ? WqT : (z == 1) ? WkT : WvT;
  const float* bias = (z == 0) ? bq  : (z == 1) ? bk  : bv;
  short* outp       = (z == 0) ? Qb  : (z == 1) ? Kb  : Vtb;
  const int mb = blockIdx.y * 128, nb = blockIdx.x * 128;
  v4f acc[4][4] = {};
  gemm_core<128>(A + (size_t)mb * 1024, Bt + (size_t)nb * 1024, As, Bs, acc);

  const int lane = threadIdx.x & 63, w = threadIdx.x >> 6;
  const int quad = lane >> 4, c15 = lane & 15;
  const int wr = (w >> 1) * 64, wc = (w & 1) * 64;
  const bool vmode = (z == 2);
#pragma unroll
  for (int nt = 0; nt < 4; ++nt) {
    const int gn = nb + wc + nt * 16 + c15;
    const float bb = bias[gn];
    const int h = gn >> 6, e = gn & 63;
#pragma unroll
    for (int mt = 0; mt < 4; ++mt) {
      if (!vmode) {
#pragma unroll
        for (int r = 0; r < 4; ++r) {
          const int gm = mb + wr + mt * 16 + quad * 4 + r;
          const int bi = gm >> 10, s = gm & 1023;
          const size_t base = (size_t)(bi * 16 + h) * 65536;
          outp[base + (size_t)s * 64 + e] = f2bf(acc[mt][nt][r] + bb);
        }
      } else {
        const int gm0 = mb + wr + mt * 16 + quad * 4;
        const int bi = gm0 >> 10, s0 = gm0 & 1023;
        const size_t base = (size_t)(bi * 16 + h) * 65536;
        short4 st = { f2bf(acc[mt][nt][0] + bb), f2bf(acc[mt][nt][1] + bb),
                      f2bf(acc[mt][nt][2] + bb), f2bf(acc[mt][nt][3] + bb) };
        *(short4*)&outp[base + (size_t)e * 1024 + s0] = st;
      }
    }
  }
}

// ---------------- output projection (64x128 tiles -> 512 blocks, 2/CU) ----------------
__global__ __launch_bounds__(256, 3) void out_gemm(
    const short* __restrict__ AV, const short* __restrict__ WoT,
    const float* __restrict__ bo, float* __restrict__ outp) {
  __shared__ short As[2048];
  __shared__ short Bs[4096];
  const int mb = blockIdx.y * 64, nb = blockIdx.x * 128;
  v4f acc[2][4] = {};
  gemm_core<64>(AV + (size_t)mb * 1024, WoT + (size_t)nb * 1024, As, Bs, acc);
  const int lane = threadIdx.x & 63, w = threadIdx.x >> 6;
  const int quad = lane >> 4, c15 = lane & 15;
  const int wr = (w >> 1) * 32, wc = (w & 1) * 64;
#pragma unroll
  for (int nt = 0; nt < 4; ++nt) {
    const int gn = nb + wc + nt * 16 + c15;
    const float bb = bo[gn];
#pragma unroll
    for (int mt = 0; mt < 2; ++mt)
#pragma unroll
      for (int r = 0; r < 4; ++r) {
        const int gm = mb + wr + mt * 16 + quad * 4 + r;
        outp[(size_t)gm * 1024 + gn] = acc[mt][nt][r] + bb;
      }
  }
}

// ---------------- flash attention (unchanged from round 5) ----------------
__global__ __launch_bounds__(256, 2) void attn_kernel(
    const short* __restrict__ Qb, const short* __restrict__ Kb,
    const short* __restrict__ Vtb, const int* __restrict__ lens,
    short* __restrict__ AVb) {
  __shared__ short Ks[2][4096];
  __shared__ short Vs[2][4096];
  const int tid = threadIdx.x, lane = tid & 63, w = tid >> 6;
  const int quad = lane >> 4, c15 = lane & 15;
  const int flat = blockIdx.x;
  const int bh = (flat & 7) + 8 * ((flat >> 3) & 7);   // XCD-L2 locality swizzle
  const int qg = flat >> 6;
  const int b = bh >> 4, h = bh & 15;
  const short* Qp = Qb  + (size_t)bh * 65536;
  const short* Kp = Kb  + (size_t)bh * 65536;
  const short* Vp = Vtb + (size_t)bh * 65536;
  const int len = lens[b];
  const int row0 = qg * 128 + w * 32;

  v8s bq_[2][2];
#pragma unroll
  for (int mg = 0; mg < 2; ++mg)
#pragma unroll
    for (int kf = 0; kf < 2; ++kf)
      bq_[mg][kf] = *(const v8s*)(Qp + (size_t)(row0 + mg * 16 + c15) * 64 + kf * 32 + quad * 8);

  float scale[2];
#pragma unroll
  for (int mg = 0; mg < 2; ++mg)
    scale[mg] = (row0 + mg * 16 + c15 < len) ? 0.125f : 0.0f;

  float sm[2] = { 0.f, 0.f };
  v4f o[2][4] = {};          // O^T: row=dh=t*16+quad*4+r, col=query=c15

  const int srow = tid >> 3, spart = tid & 7;
  const int gpart = spart ^ (srow & 7);
  const int kgo0 = srow * 64 + gpart * 8, kgo1 = (srow + 32) * 64 + gpart * 8;
  const int vgo0 = srow * 1024 + gpart * 8, vgo1 = (srow + 32) * 1024 + gpart * 8;
  const int l0 = tid * 8, l1 = 2048 + tid * 8;

  const int c7 = c15 & 7;
  const int krow = c15 * 128;
  const int koff0 = krow + ((quad) ^ c7) * 16;
  const int koff1 = krow + ((4 + quad) ^ c7) * 16;
  const int q2 = quad >> 1, h8 = (quad & 1) * 8;
  int voff[4];
#pragma unroll
  for (int nt = 0; nt < 4; ++nt)
    voff[nt] = krow + ((2 * nt + q2) ^ c7) * 16 + h8;

  glds16(Kp + kgo0, (char*)Ks[0] + l0 * 2);
  glds16(Kp + kgo1, (char*)Ks[0] + l1 * 2);
  glds16(Vp + vgo0, (char*)Vs[0] + l0 * 2);
  glds16(Vp + vgo1, (char*)Vs[0] + l1 * 2);

  for (int kb = 0; kb < 16; ++kb) {
    const int cur = kb & 1, nxt = cur ^ 1;
    __syncthreads();

    if (kb < 15) {
      const short* kt = Kp + (size_t)(kb + 1) * 4096;
      const short* vt = Vp + (kb + 1) * 64;
      glds16(kt + kgo0, (char*)Ks[nxt] + l0 * 2);
      glds16(kt + kgo1, (char*)Ks[nxt] + l1 * 2);
      glds16(vt + vgo0, (char*)Vs[nxt] + l0 * 2);
      glds16(vt + vgo1, (char*)Vs[nxt] + l1 * 2);
    }

    v8s ak[4][2];
#pragma unroll
    for (int nt = 0; nt < 4; ++nt) {
      ak[nt][0] = *(const v8s*)((const char*)Ks[cur] + nt * 2048 + koff0);
      ak[nt][1] = *(const v8s*)((const char*)Ks[cur] + nt * 2048 + koff1);
    }
    v4s av[4][4];
#pragma unroll
    for (int t = 0; t < 4; ++t)
#pragma unroll
      for (int nt = 0; nt < 4; ++nt)
        av[t][nt] = *(const v4s*)((const char*)Vs[cur] + t * 2048 + voff[nt]);

    v4f sc[2][4];
#pragma unroll
    for (int mg = 0; mg < 2; ++mg)
#pragma unroll
      for (int nt = 0; nt < 4; ++nt) {
        v4f z = {};
#pragma unroll
        for (int kf = 0; kf < 2; ++kf)
          z = __builtin_amdgcn_mfma_f32_16x16x32_bf16(ak[nt][kf], bq_[mg][kf], z, 0, 0, 0);
        sc[mg][nt] = z;
      }

    v4s pb[2][4];
#pragma unroll
    for (int mg = 0; mg < 2; ++mg)
#pragma unroll
      for (int nt = 0; nt < 4; ++nt) {
        v4s pv;
#pragma unroll
        for (int r = 0; r < 4; ++r) {
          float p = __expf(sc[mg][nt][r] * scale[mg]);
          sm[mg] += p;
          pv[r] = f2bf(p);
        }
        pb[mg][nt] = pv;
      }

#pragma unroll
    for (int mg = 0; mg < 2; ++mg)
#pragma unroll
      for (int t = 0; t < 4; ++t)
#pragma unroll
        for (int nt = 0; nt < 4; ++nt)
          o[mg][t] = __builtin_amdgcn_mfma_f32_16x16x16bf16_1k(av[t][nt], pb[mg][nt], o[mg][t], 0, 0, 0);
  }

#pragma unroll
  for (int mg = 0; mg < 2; ++mg) {
    sm[mg] += __shfl_xor(sm[mg], 16);
    sm[mg] += __shfl_xor(sm[mg], 32);
  }

#pragma unroll
  for (int mg = 0; mg < 2; ++mg) {
    const float inv = 1.0f / sm[mg];
    const size_t rowbase = (size_t)(b * 1024 + row0 + mg * 16 + c15) * 1024 + h * 64;
#pragma unroll
    for (int t = 0; t < 4; ++t) {
      short4 st = { f2bf(o[mg][t][0] * inv), f2bf(o[mg][t][1] * inv),
                    f2bf(o[mg][t][2] * inv), f2bf(o[mg][t][3] * inv) };
      *(short4*)&AVb[rowbase + t * 16 + quad * 4] = st;
    }
  }
}

// ---------------- launch ----------------
extern "C" void kernel_launch(void* const* d_in, const int* in_sizes, int n_in,
                              void* d_out, int out_size, void* d_ws, size_t ws_size,
                              hipStream_t stream) {
  const float* xQ = (const float*)d_in[0];
  const float* xK = (const float*)d_in[1];
  const float* xV = (const float*)d_in[2];
  const int* lens = (const int*)d_in[3];
  const float* Wq = (const float*)d_in[4];
  const float* bq = (const float*)d_in[5];
  const float* Wk = (const float*)d_in[6];
  const float* bk = (const float*)d_in[7];
  const float* Wv = (const float*)d_in[8];
  const float* bv = (const float*)d_in[9];
  const float* Wo = (const float*)d_in[10];
  const float* bo = (const float*)d_in[11];
  float* out = (float*)d_out;

  char* ws = (char*)d_ws;
  short* xQb = (short*)(ws + 0);                 // 8 MB  [4096][1024] bf16
  short* xKb = (short*)(ws + 8388608);
  short* xVb = (short*)(ws + 16777216);
  short* WqT = (short*)(ws + 25165824);          // 2 MB  [n=h*64+e][d]
  short* WkT = (short*)(ws + 27262976);
  short* WvT = (short*)(ws + 29360128);
  short* WoT = (short*)(ws + 31457280);          // 2 MB  Wo^T [n][k]
  short* Qb  = (short*)(ws + 33554432);          // 8 MB  [b,h,s,e]
  short* Kb  = (short*)(ws + 41943040);          // 8 MB  [b,h,s,e]
  short* Vtb = (short*)(ws + 50331648);          // 8 MB  [b,h,e,s]
  short* AVb = (short*)(ws + 58720256);          // 8 MB  [b,s,h*64+e]

  cast3_f32_bf16<<<dim3(4096, 1, 3), 256, 0, stream>>>(xQ, xK, xV, xQb, xKb, xVb, 1048576);
  transpose_w_all<<<dim3(16, 16, 4), 256, 0, stream>>>(Wq, Wk, Wv, Wo, WqT, WkT, WvT, WoT);
  proj_gemm<<<dim3(8, 32, 3), 256, 0, stream>>>(xQb, xKb, xVb, WqT, WkT, WvT,
                                                bq, bk, bv, Qb, Kb, Vtb);
  attn_kernel<<<dim3(512), 256, 0, stream>>>(Qb, Kb, Vtb, lens, AVb);
  out_gemm<<<dim3(8, 64, 1), 256, 0, stream>>>(AVb, WoT, bo, out);
}

// Round 7
// 205.299 us; speedup vs baseline: 1.3430x; 1.0206x over previous
//
#include <hip/hip_runtime.h>
#include <stdint.h>

typedef short v8s __attribute__((ext_vector_type(8)));
typedef short v4s __attribute__((ext_vector_type(4)));
typedef float v4f __attribute__((ext_vector_type(4)));

#define AS1 __attribute__((address_space(1)))
#define AS3 __attribute__((address_space(3)))

__device__ __forceinline__ void glds16(const void* g, void* l) {
  __builtin_amdgcn_global_load_lds((const AS1 void*)g, (AS3 void*)l, 16, 0, 0);
}

__device__ __forceinline__ short f2bf(float f) {
  uint32_t u = __float_as_uint(f);
  u += 0x7fffu + ((u >> 16) & 1u);   // RNE; inputs are finite
  return (short)(u >> 16);
}

// ---------------- prep kernels ----------------

__global__ __launch_bounds__(256) void cast3_f32_bf16(
    const float* __restrict__ a, const float* __restrict__ b, const float* __restrict__ c,
    short* __restrict__ oa, short* __restrict__ ob, short* __restrict__ oc, int n4) {
  const float* in = (blockIdx.z == 0) ? a : (blockIdx.z == 1) ? b : c;
  short* out      = (blockIdx.z == 0) ? oa : (blockIdx.z == 1) ? ob : oc;
  int i = blockIdx.x * 256 + threadIdx.x;
  if (i < n4) {
    float4 v = ((const float4*)in)[i];
    short4 o = { f2bf(v.x), f2bf(v.y), f2bf(v.z), f2bf(v.w) };
    ((short4*)out)[i] = o;
  }
}

// All weight transposes in one dispatch. grid (16,16,4):
//  z<3 : per-head W (z picks Wq/Wk/Wv), slice=blockIdx.y, rb=blockIdx.x*64, 1024x64 -> 64x1024
//  z=3 : Wo 1024x1024 -> WoT, rb=blockIdx.x*64, cb=blockIdx.y*64
__global__ __launch_bounds__(256) void transpose_w_all(
    const float* __restrict__ wq, const float* __restrict__ wk, const float* __restrict__ wv,
    const float* __restrict__ wo,
    short* __restrict__ oq, short* __restrict__ ok, short* __restrict__ ov,
    short* __restrict__ oo) {
  __shared__ float tile[64][65];
  const int z = blockIdx.z;
  const float* in;
  short* out;
  int C, R, rb, cb;
  if (z < 3) {
    const int slice = blockIdx.y;
    in  = ((z == 0) ? wq : (z == 1) ? wk : wv) + (size_t)slice * 65536;
    out = ((z == 0) ? oq : (z == 1) ? ok : ov) + (size_t)slice * 65536;
    C = 64; R = 1024; rb = blockIdx.x * 64; cb = 0;
  } else {
    in = wo; out = oo;
    C = 1024; R = 1024; rb = blockIdx.x * 64; cb = blockIdx.y * 64;
  }
  int t = threadIdx.x;
  int col = t & 63, r0 = t >> 6;
#pragma unroll
  for (int i = 0; i < 16; ++i) {
    int row = r0 + i * 4;
    tile[row][col] = in[(size_t)(rb + row) * C + cb + col];
  }
  __syncthreads();
#pragma unroll
  for (int i = 0; i < 16; ++i) {
    int orow = r0 + i * 4;
    out[(size_t)(cb + orow) * R + rb + col] = f2bf(tile[col][orow]);
  }
}

// ---------------- MRx128 GEMM core (m97 structure), MR in {64,128} ----------------
template <int MR>
__device__ __forceinline__ void gemm_core(const short* __restrict__ Ag,
                                          const short* __restrict__ Bg,
                                          short* As, short* Bs,
                                          v4f (&acc)[MR / 32][4]) {
  constexpr int MT = MR / 32;
  const int tid  = threadIdx.x;
  const int lane = tid & 63;
  const int w    = tid >> 6;
  const int quad = lane >> 4;
  const int c15  = lane & 15;
  const int wr   = (w >> 1) * (MR / 2);
  const int wc   = (w & 1) * 64;

  const int r0 = tid >> 2, p0 = tid & 3;
  const short* g0 = Ag + (size_t)r0 * 1024 + p0 * 8;
  const short* g1 = g0 + 64 * 1024;               // used only when MR==128
  const short* h0 = Bg + (size_t)r0 * 1024 + p0 * 8;
  const short* h1 = h0 + 64 * 1024;
  short* lA0 = As + tid * 8;
  short* lA1 = As + (256 + tid) * 8;
  short* lB0 = Bs + tid * 8;
  short* lB1 = Bs + (256 + tid) * 8;

  for (int kb = 0; kb < 32; ++kb) {
    __syncthreads();
    glds16(g0, lA0);
    if constexpr (MR == 128) glds16(g1, lA1);
    glds16(h0, lB0); glds16(h1, lB1);
    g0 += 32; h0 += 32; h1 += 32;
    if constexpr (MR == 128) g1 += 32;
    __syncthreads();

    v8s a[MT], b[4];
#pragma unroll
    for (int mt = 0; mt < MT; ++mt)
      a[mt] = *(const v8s*)(As + (wr + mt * 16 + c15) * 32 + quad * 8);
#pragma unroll
    for (int nt = 0; nt < 4; ++nt)
      b[nt] = *(const v8s*)(Bs + (wc + nt * 16 + c15) * 32 + quad * 8);
#pragma unroll
    for (int mt = 0; mt < MT; ++mt)
#pragma unroll
      for (int nt = 0; nt < 4; ++nt)
        acc[mt][nt] = __builtin_amdgcn_mfma_f32_16x16x32_bf16(a[mt], b[nt], acc[mt][nt], 0, 0, 0);
  }
}

// ---------------- QKV projection (128x128 tiles, XCD-patch swizzle) ----------------
// flat grid 768. XCD = lin&7 (round-robin dispatch). XCD p gets row-tiles 4p..4p+3
// x all 8 col-tiles x all z: per-XCD-L2 set = 1MB A-rows (disjoint!) + 2MB B = 3MB.
// A fetched from HBM once total; B once per XCD.
__global__ __launch_bounds__(256, 3) void proj_gemm(
    const short* __restrict__ xQ, const short* __restrict__ xK, const short* __restrict__ xV,
    const short* __restrict__ WqT, const short* __restrict__ WkT, const short* __restrict__ WvT,
    const float* __restrict__ bq, const float* __restrict__ bk, const float* __restrict__ bv,
    short* __restrict__ Qb, short* __restrict__ Kb, short* __restrict__ Vtb) {
  __shared__ short As[4096];
  __shared__ short Bs[4096];
  const int lin = blockIdx.x;
  const int z = lin >> 8;
  const int r = lin & 255;
  const int nb = ((r >> 3) & 7) * 128;
  const int mb = (((r & 7) << 2) + (r >> 6)) * 128;
  const short* A    = (z == 0) ? xQ  : (z == 1) ? xK  : xV;
  const short* Bt   = (z == 0) ? WqT : (z == 1) ? WkT : WvT;
  const float* bias = (z == 0) ? bq  : (z == 1) ? bk  : bv;
  short* outp       = (z == 0) ? Qb  : (z == 1) ? Kb  : Vtb;
  v4f acc[4][4] = {};
  gemm_core<128>(A + (size_t)mb * 1024, Bt + (size_t)nb * 1024, As, Bs, acc);

  const int lane = threadIdx.x & 63, w = threadIdx.x >> 6;
  const int quad = lane >> 4, c15 = lane & 15;
  const int wr = (w >> 1) * 64, wc = (w & 1) * 64;
  const bool vmode = (z == 2);
#pragma unroll
  for (int nt = 0; nt < 4; ++nt) {
    const int gn = nb + wc + nt * 16 + c15;
    const float bb = bias[gn];
    const int h = gn >> 6, e = gn & 63;
#pragma unroll
    for (int mt = 0; mt < 4; ++mt) {
      if (!vmode) {
#pragma unroll
        for (int rr = 0; rr < 4; ++rr) {
          const int gm = mb + wr + mt * 16 + quad * 4 + rr;
          const int bi = gm >> 10, s = gm & 1023;
          const size_t base = (size_t)(bi * 16 + h) * 65536;
          outp[base + (size_t)s * 64 + e] = f2bf(acc[mt][nt][rr] + bb);
        }
      } else {
        const int gm0 = mb + wr + mt * 16 + quad * 4;
        const int bi = gm0 >> 10, s0 = gm0 & 1023;
        const size_t base = (size_t)(bi * 16 + h) * 65536;
        short4 st = { f2bf(acc[mt][nt][0] + bb), f2bf(acc[mt][nt][1] + bb),
                      f2bf(acc[mt][nt][2] + bb), f2bf(acc[mt][nt][3] + bb) };
        *(short4*)&outp[base + (size_t)e * 1024 + s0] = st;
      }
    }
  }
}

// ---------------- output projection (64x128 tiles, XCD-patch swizzle) ----------------
// flat grid 512. XCD p gets row-tiles 8p..8p+7 x all 8 col-tiles: 1MB A + 2MB B in L2.
__global__ __launch_bounds__(256, 3) void out_gemm(
    const short* __restrict__ AV, const short* __restrict__ WoT,
    const float* __restrict__ bo, float* __restrict__ outp) {
  __shared__ short As[2048];
  __shared__ short Bs[4096];
  const int lin = blockIdx.x;
  const int nb = ((lin >> 3) & 7) * 128;
  const int mb = (((lin & 7) << 3) + (lin >> 6)) * 64;
  v4f acc[2][4] = {};
  gemm_core<64>(AV + (size_t)mb * 1024, WoT + (size_t)nb * 1024, As, Bs, acc);
  const int lane = threadIdx.x & 63, w = threadIdx.x >> 6;
  const int quad = lane >> 4, c15 = lane & 15;
  const int wr = (w >> 1) * 32, wc = (w & 1) * 64;
#pragma unroll
  for (int nt = 0; nt < 4; ++nt) {
    const int gn = nb + wc + nt * 16 + c15;
    const float bb = bo[gn];
#pragma unroll
    for (int mt = 0; mt < 2; ++mt)
#pragma unroll
      for (int r = 0; r < 4; ++r) {
        const int gm = mb + wr + mt * 16 + quad * 4 + r;
        outp[(size_t)gm * 1024 + gn] = acc[mt][nt][r] + bb;
      }
  }
}

// ---------------- flash attention (unchanged from round 5) ----------------
__global__ __launch_bounds__(256, 2) void attn_kernel(
    const short* __restrict__ Qb, const short* __restrict__ Kb,
    const short* __restrict__ Vtb, const int* __restrict__ lens,
    short* __restrict__ AVb) {
  __shared__ short Ks[2][4096];
  __shared__ short Vs[2][4096];
  const int tid = threadIdx.x, lane = tid & 63, w = tid >> 6;
  const int quad = lane >> 4, c15 = lane & 15;
  const int flat = blockIdx.x;
  const int bh = (flat & 7) + 8 * ((flat >> 3) & 7);   // XCD-L2 locality swizzle
  const int qg = flat >> 6;
  const int b = bh >> 4, h = bh & 15;
  const short* Qp = Qb  + (size_t)bh * 65536;
  const short* Kp = Kb  + (size_t)bh * 65536;
  const short* Vp = Vtb + (size_t)bh * 65536;
  const int len = lens[b];
  const int row0 = qg * 128 + w * 32;

  v8s bq_[2][2];
#pragma unroll
  for (int mg = 0; mg < 2; ++mg)
#pragma unroll
    for (int kf = 0; kf < 2; ++kf)
      bq_[mg][kf] = *(const v8s*)(Qp + (size_t)(row0 + mg * 16 + c15) * 64 + kf * 32 + quad * 8);

  float scale[2];
#pragma unroll
  for (int mg = 0; mg < 2; ++mg)
    scale[mg] = (row0 + mg * 16 + c15 < len) ? 0.125f : 0.0f;

  float sm[2] = { 0.f, 0.f };
  v4f o[2][4] = {};          // O^T: row=dh=t*16+quad*4+r, col=query=c15

  const int srow = tid >> 3, spart = tid & 7;
  const int gpart = spart ^ (srow & 7);
  const int kgo0 = srow * 64 + gpart * 8, kgo1 = (srow + 32) * 64 + gpart * 8;
  const int vgo0 = srow * 1024 + gpart * 8, vgo1 = (srow + 32) * 1024 + gpart * 8;
  const int l0 = tid * 8, l1 = 2048 + tid * 8;

  const int c7 = c15 & 7;
  const int krow = c15 * 128;
  const int koff0 = krow + ((quad) ^ c7) * 16;
  const int koff1 = krow + ((4 + quad) ^ c7) * 16;
  const int q2 = quad >> 1, h8 = (quad & 1) * 8;
  int voff[4];
#pragma unroll
  for (int nt = 0; nt < 4; ++nt)
    voff[nt] = krow + ((2 * nt + q2) ^ c7) * 16 + h8;

  glds16(Kp + kgo0, (char*)Ks[0] + l0 * 2);
  glds16(Kp + kgo1, (char*)Ks[0] + l1 * 2);
  glds16(Vp + vgo0, (char*)Vs[0] + l0 * 2);
  glds16(Vp + vgo1, (char*)Vs[0] + l1 * 2);

  for (int kb = 0; kb < 16; ++kb) {
    const int cur = kb & 1, nxt = cur ^ 1;
    __syncthreads();

    if (kb < 15) {
      const short* kt = Kp + (size_t)(kb + 1) * 4096;
      const short* vt = Vp + (kb + 1) * 64;
      glds16(kt + kgo0, (char*)Ks[nxt] + l0 * 2);
      glds16(kt + kgo1, (char*)Ks[nxt] + l1 * 2);
      glds16(vt + vgo0, (char*)Vs[nxt] + l0 * 2);
      glds16(vt + vgo1, (char*)Vs[nxt] + l1 * 2);
    }

    v8s ak[4][2];
#pragma unroll
    for (int nt = 0; nt < 4; ++nt) {
      ak[nt][0] = *(const v8s*)((const char*)Ks[cur] + nt * 2048 + koff0);
      ak[nt][1] = *(const v8s*)((const char*)Ks[cur] + nt * 2048 + koff1);
    }
    v4s av[4][4];
#pragma unroll
    for (int t = 0; t < 4; ++t)
#pragma unroll
      for (int nt = 0; nt < 4; ++nt)
        av[t][nt] = *(const v4s*)((const char*)Vs[cur] + t * 2048 + voff[nt]);

    v4f sc[2][4];
#pragma unroll
    for (int mg = 0; mg < 2; ++mg)
#pragma unroll
      for (int nt = 0; nt < 4; ++nt) {
        v4f z = {};
#pragma unroll
        for (int kf = 0; kf < 2; ++kf)
          z = __builtin_amdgcn_mfma_f32_16x16x32_bf16(ak[nt][kf], bq_[mg][kf], z, 0, 0, 0);
        sc[mg][nt] = z;
      }

    v4s pb[2][4];
#pragma unroll
    for (int mg = 0; mg < 2; ++mg)
#pragma unroll
      for (int nt = 0; nt < 4; ++nt) {
        v4s pv;
#pragma unroll
        for (int r = 0; r < 4; ++r) {
          float p = __expf(sc[mg][nt][r] * scale[mg]);
          sm[mg] += p;
          pv[r] = f2bf(p);
        }
        pb[mg][nt] = pv;
      }

#pragma unroll
    for (int mg = 0; mg < 2; ++mg)
#pragma unroll
      for (int t = 0; t < 4; ++t)
#pragma unroll
        for (int nt = 0; nt < 4; ++nt)
          o[mg][t] = __builtin_amdgcn_mfma_f32_16x16x16bf16_1k(av[t][nt], pb[mg][nt], o[mg][t], 0, 0, 0);
  }

#pragma unroll
  for (int mg = 0; mg < 2; ++mg) {
    sm[mg] += __shfl_xor(sm[mg], 16);
    sm[mg] += __shfl_xor(sm[mg], 32);
  }

#pragma unroll
  for (int mg = 0; mg < 2; ++mg) {
    const float inv = 1.0f / sm[mg];
    const size_t rowbase = (size_t)(b * 1024 + row0 + mg * 16 + c15) * 1024 + h * 64;
#pragma unroll
    for (int t = 0; t < 4; ++t) {
      short4 st = { f2bf(o[mg][t][0] * inv), f2bf(o[mg][t][1] * inv),
                    f2bf(o[mg][t][2] * inv), f2bf(o[mg][t][3] * inv) };
      *(short4*)&AVb[rowbase + t * 16 + quad * 4] = st;
    }
  }
}

// ---------------- launch ----------------
extern "C" void kernel_launch(void* const* d_in, const int* in_sizes, int n_in,
                              void* d_out, int out_size, void* d_ws, size_t ws_size,
                              hipStream_t stream) {
  const float* xQ = (const float*)d_in[0];
  const float* xK = (const float*)d_in[1];
  const float* xV = (const float*)d_in[2];
  const int* lens = (const int*)d_in[3];
  const float* Wq = (const float*)d_in[4];
  const float* bq = (const float*)d_in[5];
  const float* Wk = (const float*)d_in[6];
  const float* bk = (const float*)d_in[7];
  const float* Wv = (const float*)d_in[8];
  const float* bv = (const float*)d_in[9];
  const float* Wo = (const float*)d_in[10];
  const float* bo = (const float*)d_in[11];
  float* out = (float*)d_out;

  char* ws = (char*)d_ws;
  short* xQb = (short*)(ws + 0);                 // 8 MB  [4096][1024] bf16
  short* xKb = (short*)(ws + 8388608);
  short* xVb = (short*)(ws + 16777216);
  short* WqT = (short*)(ws + 25165824);          // 2 MB  [n=h*64+e][d]
  short* WkT = (short*)(ws + 27262976);
  short* WvT = (short*)(ws + 29360128);
  short* WoT = (short*)(ws + 31457280);          // 2 MB  Wo^T [n][k]
  short* Qb  = (short*)(ws + 33554432);          // 8 MB  [b,h,s,e]
  short* Kb  = (short*)(ws + 41943040);          // 8 MB  [b,h,s,e]
  short* Vtb = (short*)(ws + 50331648);          // 8 MB  [b,h,e,s]
  short* AVb = (short*)(ws + 58720256);          // 8 MB  [b,s,h*64+e]

  cast3_f32_bf16<<<dim3(4096, 1, 3), 256, 0, stream>>>(xQ, xK, xV, xQb, xKb, xVb, 1048576);
  transpose_w_all<<<dim3(16, 16, 4), 256, 0, stream>>>(Wq, Wk, Wv, Wo, WqT, WkT, WvT, WoT);
  proj_gemm<<<dim3(768), 256, 0, stream>>>(xQb, xKb, xVb, WqT, WkT, WvT,
                                           bq, bk, bv, Qb, Kb, Vtb);
  attn_kernel<<<dim3(512), 256, 0, stream>>>(Qb, Kb, Vtb, lens, AVb);
  out_gemm<<<dim3(512), 256, 0, stream>>>(AVb, WoT, bo, out);
}

// Round 8
// 204.909 us; speedup vs baseline: 1.3455x; 1.0019x over previous
//
#include <hip/hip_runtime.h>
#include <stdint.h>

typedef short v8s __attribute__((ext_vector_type(8)));
typedef short v4s __attribute__((ext_vector_type(4)));
typedef float v4f __attribute__((ext_vector_type(4)));

#define AS1 __attribute__((address_space(1)))
#define AS3 __attribute__((address_space(3)))

__device__ __forceinline__ void glds16(const void* g, void* l) {
  __builtin_amdgcn_global_load_lds((const AS1 void*)g, (AS3 void*)l, 16, 0, 0);
}

__device__ __forceinline__ short f2bf(float f) {
  uint32_t u = __float_as_uint(f);
  u += 0x7fffu + ((u >> 16) & 1u);   // RNE; inputs are finite
  return (short)(u >> 16);
}

// ---------------- prep kernels ----------------

__global__ __launch_bounds__(256) void cast3_f32_bf16(
    const float* __restrict__ a, const float* __restrict__ b, const float* __restrict__ c,
    short* __restrict__ oa, short* __restrict__ ob, short* __restrict__ oc, int n4) {
  const float* in = (blockIdx.z == 0) ? a : (blockIdx.z == 1) ? b : c;
  short* out      = (blockIdx.z == 0) ? oa : (blockIdx.z == 1) ? ob : oc;
  int i = blockIdx.x * 256 + threadIdx.x;
  if (i < n4) {
    float4 v = ((const float4*)in)[i];
    short4 o = { f2bf(v.x), f2bf(v.y), f2bf(v.z), f2bf(v.w) };
    ((short4*)out)[i] = o;
  }
}

// All weight transposes in one dispatch. grid (16,16,4):
//  z<3 : per-head W (z picks Wq/Wk/Wv), slice=blockIdx.y, rb=blockIdx.x*64, 1024x64 -> 64x1024
//  z=3 : Wo 1024x1024 -> WoT, rb=blockIdx.x*64, cb=blockIdx.y*64
__global__ __launch_bounds__(256) void transpose_w_all(
    const float* __restrict__ wq, const float* __restrict__ wk, const float* __restrict__ wv,
    const float* __restrict__ wo,
    short* __restrict__ oq, short* __restrict__ ok, short* __restrict__ ov,
    short* __restrict__ oo) {
  __shared__ float tile[64][65];
  const int z = blockIdx.z;
  const float* in;
  short* out;
  int C, R, rb, cb;
  if (z < 3) {
    const int slice = blockIdx.y;
    in  = ((z == 0) ? wq : (z == 1) ? wk : wv) + (size_t)slice * 65536;
    out = ((z == 0) ? oq : (z == 1) ? ok : ov) + (size_t)slice * 65536;
    C = 64; R = 1024; rb = blockIdx.x * 64; cb = 0;
  } else {
    in = wo; out = oo;
    C = 1024; R = 1024; rb = blockIdx.x * 64; cb = blockIdx.y * 64;
  }
  int t = threadIdx.x;
  int col = t & 63, r0 = t >> 6;
#pragma unroll
  for (int i = 0; i < 16; ++i) {
    int row = r0 + i * 4;
    tile[row][col] = in[(size_t)(rb + row) * C + cb + col];
  }
  __syncthreads();
#pragma unroll
  for (int i = 0; i < 16; ++i) {
    int orow = r0 + i * 4;
    out[(size_t)(cb + orow) * R + rb + col] = f2bf(tile[col][orow]);
  }
}

// ---------------- MRx128 GEMM core — async 3-buffer pipeline ----------------
// m139/AITER pattern: raw s_barrier + s_waitcnt vmcnt(G) (never vmcnt(0)),
// DMA issued 2 tiles ahead so one full compute iteration covers its latency.
// WAR safe: buffer (kb+2)%3's readers ran at iter kb-1; their ds_read results
// were consumed (lgkm drained) before they reached this iter's barrier.
template <int MR>
__device__ __forceinline__ void gemm_core(const short* __restrict__ Ag,
                                          const short* __restrict__ Bg,
                                          short* As, short* Bs,
                                          v4f (&acc)[MR / 32][4]) {
  constexpr int MT = MR / 32;
  constexpr int ASZ = MR * 32;     // shorts per A buffer
  constexpr int BSZ = 128 * 32;    // shorts per B buffer
  const int tid  = threadIdx.x;
  const int lane = tid & 63;
  const int w    = tid >> 6;
  const int quad = lane >> 4;
  const int c15  = lane & 15;
  const int wr   = (w >> 1) * (MR / 2);
  const int wc   = (w & 1) * 64;

  // staging: chunk c -> row=c>>2, 16B part=c&3 ; LDS slot = c*16B (layout [row][32])
  const int r0 = tid >> 2, p0 = tid & 3;
  const short* a0 = Ag + (size_t)r0 * 1024 + p0 * 8;
  const short* a1 = a0 + 64 * 1024;               // used only when MR==128
  const short* b0 = Bg + (size_t)r0 * 1024 + p0 * 8;
  const short* b1 = b0 + 64 * 1024;
  short* lA = As + tid * 8;
  short* lB = Bs + tid * 8;

  auto issue = [&](int t, int buf) {
    const int o = t * 32;
    glds16(a0 + o, lA + buf * ASZ);
    if constexpr (MR == 128) glds16(a1 + o, lA + buf * ASZ + 2048);
    glds16(b0 + o, lB + buf * BSZ);
    glds16(b1 + o, lB + buf * BSZ + 2048);
  };

  issue(0, 0);
  issue(1, 1);

  for (int kb = 0; kb < 32; ++kb) {
    // wait only the oldest tile's DMA (G outstanding allowed), then raw barrier
    if constexpr (MR == 128)
      asm volatile("s_waitcnt vmcnt(4)\n\ts_barrier" ::: "memory");
    else
      asm volatile("s_waitcnt vmcnt(3)\n\ts_barrier" ::: "memory");

    const int t2 = kb + 2;
    issue(t2 < 32 ? t2 : 31, t2 % 3);   // dummy re-issue keeps vmcnt accounting uniform

    const short* Ab = As + (kb % 3) * ASZ;
    const short* Bb = Bs + (kb % 3) * BSZ;

    v8s a[MT], b[4];
#pragma unroll
    for (int mt = 0; mt < MT; ++mt)
      a[mt] = *(const v8s*)(Ab + (wr + mt * 16 + c15) * 32 + quad * 8);
#pragma unroll
    for (int nt = 0; nt < 4; ++nt)
      b[nt] = *(const v8s*)(Bb + (wc + nt * 16 + c15) * 32 + quad * 8);
#pragma unroll
    for (int mt = 0; mt < MT; ++mt)
#pragma unroll
      for (int nt = 0; nt < 4; ++nt)
        acc[mt][nt] = __builtin_amdgcn_mfma_f32_16x16x32_bf16(a[mt], b[nt], acc[mt][nt], 0, 0, 0);
  }
}

// ---------------- QKV projection (128x128 tiles, XCD-patch swizzle) ----------------
__global__ __launch_bounds__(256, 3) void proj_gemm(
    const short* __restrict__ xQ, const short* __restrict__ xK, const short* __restrict__ xV,
    const short* __restrict__ WqT, const short* __restrict__ WkT, const short* __restrict__ WvT,
    const float* __restrict__ bq, const float* __restrict__ bk, const float* __restrict__ bv,
    short* __restrict__ Qb, short* __restrict__ Kb, short* __restrict__ Vtb) {
  __shared__ short As[12288];   // 3 x 8 KB
  __shared__ short Bs[12288];
  const int lin = blockIdx.x;
  const int z = lin >> 8;
  const int r = lin & 255;
  const int nb = ((r >> 3) & 7) * 128;
  const int mb = (((r & 7) << 2) + (r >> 6)) * 128;
  const short* A    = (z == 0) ? xQ  : (z == 1) ? xK  : xV;
  const short* Bt   = (z == 0) ? WqT : (z == 1) ? WkT : WvT;
  const float* bias = (z == 0) ? bq  : (z == 1) ? bk  : bv;
  short* outp       = (z == 0) ? Qb  : (z == 1) ? Kb  : Vtb;
  v4f acc[4][4] = {};
  gemm_core<128>(A + (size_t)mb * 1024, Bt + (size_t)nb * 1024, As, Bs, acc);

  const int lane = threadIdx.x & 63, w = threadIdx.x >> 6;
  const int quad = lane >> 4, c15 = lane & 15;
  const int wr = (w >> 1) * 64, wc = (w & 1) * 64;
  const bool vmode = (z == 2);
#pragma unroll
  for (int nt = 0; nt < 4; ++nt) {
    const int gn = nb + wc + nt * 16 + c15;
    const float bb = bias[gn];
    const int h = gn >> 6, e = gn & 63;
#pragma unroll
    for (int mt = 0; mt < 4; ++mt) {
      if (!vmode) {
#pragma unroll
        for (int rr = 0; rr < 4; ++rr) {
          const int gm = mb + wr + mt * 16 + quad * 4 + rr;
          const int bi = gm >> 10, s = gm & 1023;
          const size_t base = (size_t)(bi * 16 + h) * 65536;
          outp[base + (size_t)s * 64 + e] = f2bf(acc[mt][nt][rr] + bb);
        }
      } else {
        const int gm0 = mb + wr + mt * 16 + quad * 4;
        const int bi = gm0 >> 10, s0 = gm0 & 1023;
        const size_t base = (size_t)(bi * 16 + h) * 65536;
        short4 st = { f2bf(acc[mt][nt][0] + bb), f2bf(acc[mt][nt][1] + bb),
                      f2bf(acc[mt][nt][2] + bb), f2bf(acc[mt][nt][3] + bb) };
        *(short4*)&outp[base + (size_t)e * 1024 + s0] = st;
      }
    }
  }
}

// ---------------- output projection (64x128 tiles, XCD-patch swizzle) ----------------
__global__ __launch_bounds__(256, 3) void out_gemm(
    const short* __restrict__ AV, const short* __restrict__ WoT,
    const float* __restrict__ bo, float* __restrict__ outp) {
  __shared__ short As[6144];    // 3 x 4 KB
  __shared__ short Bs[12288];
  const int lin = blockIdx.x;
  const int nb = ((lin >> 3) & 7) * 128;
  const int mb = (((lin & 7) << 3) + (lin >> 6)) * 64;
  v4f acc[2][4] = {};
  gemm_core<64>(AV + (size_t)mb * 1024, WoT + (size_t)nb * 1024, As, Bs, acc);
  const int lane = threadIdx.x & 63, w = threadIdx.x >> 6;
  const int quad = lane >> 4, c15 = lane & 15;
  const int wr = (w >> 1) * 32, wc = (w & 1) * 64;
#pragma unroll
  for (int nt = 0; nt < 4; ++nt) {
    const int gn = nb + wc + nt * 16 + c15;
    const float bb = bo[gn];
#pragma unroll
    for (int mt = 0; mt < 2; ++mt)
#pragma unroll
      for (int r = 0; r < 4; ++r) {
        const int gm = mb + wr + mt * 16 + quad * 4 + r;
        outp[(size_t)gm * 1024 + gn] = acc[mt][nt][r] + bb;
      }
  }
}

// ---------------- flash attention (unchanged from round 5 — control) ----------------
__global__ __launch_bounds__(256, 2) void attn_kernel(
    const short* __restrict__ Qb, const short* __restrict__ Kb,
    const short* __restrict__ Vtb, const int* __restrict__ lens,
    short* __restrict__ AVb) {
  __shared__ short Ks[2][4096];
  __shared__ short Vs[2][4096];
  const int tid = threadIdx.x, lane = tid & 63, w = tid >> 6;
  const int quad = lane >> 4, c15 = lane & 15;
  const int flat = blockIdx.x;
  const int bh = (flat & 7) + 8 * ((flat >> 3) & 7);   // XCD-L2 locality swizzle
  const int qg = flat >> 6;
  const int b = bh >> 4, h = bh & 15;
  const short* Qp = Qb  + (size_t)bh * 65536;
  const short* Kp = Kb  + (size_t)bh * 65536;
  const short* Vp = Vtb + (size_t)bh * 65536;
  const int len = lens[b];
  const int row0 = qg * 128 + w * 32;

  v8s bq_[2][2];
#pragma unroll
  for (int mg = 0; mg < 2; ++mg)
#pragma unroll
    for (int kf = 0; kf < 2; ++kf)
      bq_[mg][kf] = *(const v8s*)(Qp + (size_t)(row0 + mg * 16 + c15) * 64 + kf * 32 + quad * 8);

  float scale[2];
#pragma unroll
  for (int mg = 0; mg < 2; ++mg)
    scale[mg] = (row0 + mg * 16 + c15 < len) ? 0.125f : 0.0f;

  float sm[2] = { 0.f, 0.f };
  v4f o[2][4] = {};          // O^T: row=dh=t*16+quad*4+r, col=query=c15

  const int srow = tid >> 3, spart = tid & 7;
  const int gpart = spart ^ (srow & 7);
  const int kgo0 = srow * 64 + gpart * 8, kgo1 = (srow + 32) * 64 + gpart * 8;
  const int vgo0 = srow * 1024 + gpart * 8, vgo1 = (srow + 32) * 1024 + gpart * 8;
  const int l0 = tid * 8, l1 = 2048 + tid * 8;

  const int c7 = c15 & 7;
  const int krow = c15 * 128;
  const int koff0 = krow + ((quad) ^ c7) * 16;
  const int koff1 = krow + ((4 + quad) ^ c7) * 16;
  const int q2 = quad >> 1, h8 = (quad & 1) * 8;
  int voff[4];
#pragma unroll
  for (int nt = 0; nt < 4; ++nt)
    voff[nt] = krow + ((2 * nt + q2) ^ c7) * 16 + h8;

  glds16(Kp + kgo0, (char*)Ks[0] + l0 * 2);
  glds16(Kp + kgo1, (char*)Ks[0] + l1 * 2);
  glds16(Vp + vgo0, (char*)Vs[0] + l0 * 2);
  glds16(Vp + vgo1, (char*)Vs[0] + l1 * 2);

  for (int kb = 0; kb < 16; ++kb) {
    const int cur = kb & 1, nxt = cur ^ 1;
    __syncthreads();

    if (kb < 15) {
      const short* kt = Kp + (size_t)(kb + 1) * 4096;
      const short* vt = Vp + (kb + 1) * 64;
      glds16(kt + kgo0, (char*)Ks[nxt] + l0 * 2);
      glds16(kt + kgo1, (char*)Ks[nxt] + l1 * 2);
      glds16(vt + vgo0, (char*)Vs[nxt] + l0 * 2);
      glds16(vt + vgo1, (char*)Vs[nxt] + l1 * 2);
    }

    v8s ak[4][2];
#pragma unroll
    for (int nt = 0; nt < 4; ++nt) {
      ak[nt][0] = *(const v8s*)((const char*)Ks[cur] + nt * 2048 + koff0);
      ak[nt][1] = *(const v8s*)((const char*)Ks[cur] + nt * 2048 + koff1);
    }
    v4s av[4][4];
#pragma unroll
    for (int t = 0; t < 4; ++t)
#pragma unroll
      for (int nt = 0; nt < 4; ++nt)
        av[t][nt] = *(const v4s*)((const char*)Vs[cur] + t * 2048 + voff[nt]);

    v4f sc[2][4];
#pragma unroll
    for (int mg = 0; mg < 2; ++mg)
#pragma unroll
      for (int nt = 0; nt < 4; ++nt) {
        v4f z = {};
#pragma unroll
        for (int kf = 0; kf < 2; ++kf)
          z = __builtin_amdgcn_mfma_f32_16x16x32_bf16(ak[nt][kf], bq_[mg][kf], z, 0, 0, 0);
        sc[mg][nt] = z;
      }

    v4s pb[2][4];
#pragma unroll
    for (int mg = 0; mg < 2; ++mg)
#pragma unroll
      for (int nt = 0; nt < 4; ++nt) {
        v4s pv;
#pragma unroll
        for (int r = 0; r < 4; ++r) {
          float p = __expf(sc[mg][nt][r] * scale[mg]);
          sm[mg] += p;
          pv[r] = f2bf(p);
        }
        pb[mg][nt] = pv;
      }

#pragma unroll
    for (int mg = 0; mg < 2; ++mg)
#pragma unroll
      for (int t = 0; t < 4; ++t)
#pragma unroll
        for (int nt = 0; nt < 4; ++nt)
          o[mg][t] = __builtin_amdgcn_mfma_f32_16x16x16bf16_1k(av[t][nt], pb[mg][nt], o[mg][t], 0, 0, 0);
  }

#pragma unroll
  for (int mg = 0; mg < 2; ++mg) {
    sm[mg] += __shfl_xor(sm[mg], 16);
    sm[mg] += __shfl_xor(sm[mg], 32);
  }

#pragma unroll
  for (int mg = 0; mg < 2; ++mg) {
    const float inv = 1.0f / sm[mg];
    const size_t rowbase = (size_t)(b * 1024 + row0 + mg * 16 + c15) * 1024 + h * 64;
#pragma unroll
    for (int t = 0; t < 4; ++t) {
      short4 st = { f2bf(o[mg][t][0] * inv), f2bf(o[mg][t][1] * inv),
                    f2bf(o[mg][t][2] * inv), f2bf(o[mg][t][3] * inv) };
      *(short4*)&AVb[rowbase + t * 16 + quad * 4] = st;
    }
  }
}

// ---------------- launch ----------------
extern "C" void kernel_launch(void* const* d_in, const int* in_sizes, int n_in,
                              void* d_out, int out_size, void* d_ws, size_t ws_size,
                              hipStream_t stream) {
  const float* xQ = (const float*)d_in[0];
  const float* xK = (const float*)d_in[1];
  const float* xV = (const float*)d_in[2];
  const int* lens = (const int*)d_in[3];
  const float* Wq = (const float*)d_in[4];
  const float* bq = (const float*)d_in[5];
  const float* Wk = (const float*)d_in[6];
  const float* bk = (const float*)d_in[7];
  const float* Wv = (const float*)d_in[8];
  const float* bv = (const float*)d_in[9];
  const float* Wo = (const float*)d_in[10];
  const float* bo = (const float*)d_in[11];
  float* out = (float*)d_out;

  char* ws = (char*)d_ws;
  short* xQb = (short*)(ws + 0);                 // 8 MB  [4096][1024] bf16
  short* xKb = (short*)(ws + 8388608);
  short* xVb = (short*)(ws + 16777216);
  short* WqT = (short*)(ws + 25165824);          // 2 MB  [n=h*64+e][d]
  short* WkT = (short*)(ws + 27262976);
  short* WvT = (short*)(ws + 29360128);
  short* WoT = (short*)(ws + 31457280);          // 2 MB  Wo^T [n][k]
  short* Qb  = (short*)(ws + 33554432);          // 8 MB  [b,h,s,e]
  short* Kb  = (short*)(ws + 41943040);          // 8 MB  [b,h,s,e]
  short* Vtb = (short*)(ws + 50331648);          // 8 MB  [b,h,e,s]
  short* AVb = (short*)(ws + 58720256);          // 8 MB  [b,s,h*64+e]

  cast3_f32_bf16<<<dim3(4096, 1, 3), 256, 0, stream>>>(xQ, xK, xV, xQb, xKb, xVb, 1048576);
  transpose_w_all<<<dim3(16, 16, 4), 256, 0, stream>>>(Wq, Wk, Wv, Wo, WqT, WkT, WvT, WoT);
  proj_gemm<<<dim3(768), 256, 0, stream>>>(xQb, xKb, xVb, WqT, WkT, WvT,
                                           bq, bk, bv, Qb, Kb, Vtb);
  attn_kernel<<<dim3(512), 256, 0, stream>>>(Qb, Kb, Vtb, lens, AVb);
  out_gemm<<<dim3(512), 256, 0, stream>>>(AVb, WoT, bo, out);
}